// Round 1
// 259.974 us; speedup vs baseline: 1.0009x; 1.0009x over previous
//
#include <hip/hip_runtime.h>
#include <hip/hip_bf16.h>
#include <math.h>

typedef float f32x4 __attribute__((ext_vector_type(4)));
typedef short s16x8 __attribute__((ext_vector_type(8)));
typedef unsigned short us16x4 __attribute__((ext_vector_type(4)));
typedef unsigned short us16x8 __attribute__((ext_vector_type(8)));
typedef unsigned int u32x2 __attribute__((ext_vector_type(2)));

#define MFMA16(a, b, c) __builtin_amdgcn_mfma_f32_16x16x32_bf16(a, b, c, 0, 0, 0)

static constexpr int B_ = 2, S_ = 2048, D_ = 1024, H_ = 16, HD_ = 64;
// Q pre-scale: HD^-0.5 * log2(e)  -> flash softmax in exp2 domain, no max needed
static constexpr float QSCALE = 0.125f * 1.44269504088896340736f;

__device__ __forceinline__ unsigned short f2bf(float f) {
    unsigned int u = __builtin_bit_cast(unsigned int, f);
    u += 0x7fffu + ((u >> 16) & 1);  // round-to-nearest-even
    return (unsigned short)(u >> 16);
}

// packed fp32x2 -> bf16x2 (lo=a, hi=b), RNE. HW inst on gfx950.
#if defined(__has_builtin) && __has_builtin(__builtin_amdgcn_cvt_pk_bf16_f32)
typedef __bf16 bf16x2v __attribute__((ext_vector_type(2)));
__device__ __forceinline__ unsigned int pk_bf16(float a, float b) {
    return __builtin_bit_cast(unsigned int, __builtin_amdgcn_cvt_pk_bf16_f32(a, b));
}
#else
__device__ __forceinline__ unsigned int pk_bf16(float a, float b) {
    return ((unsigned int)f2bf(a)) | (((unsigned int)f2bf(b)) << 16);
}
#endif

__device__ __forceinline__ void glds16(const unsigned short* g, unsigned short* l) {
    __builtin_amdgcn_global_load_lds(
        (const __attribute__((address_space(1))) void*)g,
        (__attribute__((address_space(3))) void*)l, 16, 0, 0);
}

// ---------------------------------------------------------------------------
// fp32 -> bf16 flat converts
// ---------------------------------------------------------------------------
__global__ __launch_bounds__(256) void conv3(const float* __restrict__ s0,
                                             const float* __restrict__ s1,
                                             const float* __restrict__ s2,
                                             unsigned short* __restrict__ d0,
                                             unsigned short* __restrict__ d1,
                                             unsigned short* __restrict__ d2) {
    const int z = blockIdx.z;
    const float* src = (z == 0) ? s0 : (z == 1) ? s1 : s2;
    unsigned short* dst = (z == 0) ? d0 : (z == 1) ? d1 : d2;
    int i = (blockIdx.x * 256 + threadIdx.x) * 8;
    f32x4 a = *(const f32x4*)&src[i];
    f32x4 b = *(const f32x4*)&src[i + 4];
    s16x8 o;
#pragma unroll
    for (int j = 0; j < 4; j++) { o[j] = (short)f2bf(a[j]); o[4 + j] = (short)f2bf(b[j]); }
    *(s16x8*)&dst[i] = o;
}

__global__ __launch_bounds__(256) void conv_bf16(const float* __restrict__ src,
                                                 unsigned short* __restrict__ dst) {
    int i = (blockIdx.x * 256 + threadIdx.x) * 8;
    f32x4 a = *(const f32x4*)&src[i];
    f32x4 b = *(const f32x4*)&src[i + 4];
    s16x8 o;
#pragma unroll
    for (int j = 0; j < 4; j++) { o[j] = (short)f2bf(a[j]); o[4 + j] = (short)f2bf(b[j]); }
    *(s16x8*)&dst[i] = o;
}

// ---------------------------------------------------------------------------
// Weight transpose: Wt[(h*64+e)*1024 + d] = W[h*65536 + d*64 + e]
// ---------------------------------------------------------------------------
__global__ __launch_bounds__(256) void transpose_w3(const float* __restrict__ W0,
                                                    const float* __restrict__ W1,
                                                    const float* __restrict__ W2,
                                                    unsigned short* __restrict__ Wt3) {
    const int z = blockIdx.z;
    const float* W = (z == 0) ? W0 : (z == 1) ? W1 : W2;
    unsigned short* dst = Wt3 + ((size_t)z << 20);
    const int h = blockIdx.x >> 2, dg = blockIdx.x & 3;
    const int lane = threadIdx.x & 63, w = threadIdx.x >> 6;
    const float* Wh = W + ((size_t)h << 16);
#pragma unroll
    for (int it = 0; it < 8; it++) {
        int d0 = dg * 256 + it * 32 + w * 8;
        us16x8 o;
#pragma unroll
        for (int j = 0; j < 8; j++) o[j] = f2bf(Wh[(d0 + j) * 64 + lane]);
        *(us16x8*)&dst[(size_t)(h * 64 + lane) * 1024 + d0] = o;
    }
}

// ---------------------------------------------------------------------------
// 128x128-tile bf16 GEMM core, K=1024, BK=64, global_load_lds, XOR swizzle.
// ---------------------------------------------------------------------------
__device__ __forceinline__ void gemm_core128(const unsigned short* __restrict__ A,
                                             const unsigned short* __restrict__ Bt,
                                             unsigned short* As, unsigned short* Bs,
                                             int m0, int n0, f32x4 acc[4][4]) {
    const int tid = threadIdx.x;
    const int lane = tid & 63;
    const int w = tid >> 6, wm = w & 1, wn = w >> 1;
    const int l16 = lane & 15, quad = lane >> 4;
    const int srow = tid >> 3;
    const int sg = (tid & 7) ^ (srow & 7);
    const unsigned short* Ag = A + (size_t)(m0 + srow) * 1024 + sg * 8;
    const unsigned short* Bg = Bt + (size_t)(n0 + srow) * 1024 + sg * 8;
    unsigned short* Al = As + tid * 8;
    unsigned short* Bl = Bs + tid * 8;
    const int xo = (l16 & 7);

    for (int k0 = 0; k0 < 1024; k0 += 64) {
        __syncthreads();
#pragma unroll
        for (int c = 0; c < 4; c++) {
            glds16(Ag + (size_t)c * 32 * 1024 + k0, Al + c * 2048);
            glds16(Bg + (size_t)c * 32 * 1024 + k0, Bl + c * 2048);
        }
        __syncthreads();
#pragma unroll
        for (int kc = 0; kc < 2; kc++) {
            s16x8 bf[4];
#pragma unroll
            for (int nt = 0; nt < 4; nt++)
                bf[nt] = *(const s16x8*)&Bs[(wn * 64 + nt * 16 + l16) * 64 +
                                            (((kc * 4 + quad) ^ xo) * 8)];
#pragma unroll
            for (int mt = 0; mt < 4; mt++) {
                s16x8 af = *(const s16x8*)&As[(wm * 64 + mt * 16 + l16) * 64 +
                                              (((kc * 4 + quad) ^ xo) * 8)];
#pragma unroll
                for (int nt = 0; nt < 4; nt++)
                    acc[mt][nt] = MFMA16(af, bf[nt], acc[mt][nt]);
            }
        }
    }
}

// QKV fused via grid.z: z=0 Q -> row-major [B,S,D] (pre-scaled), z=1 K -> row-major,
// z=2 V -> transposed [B,H,HD,S]. Epilogue: per-wave LDS transpose -> 16B stores.
__global__ __launch_bounds__(256) void gemm_qkv(const unsigned short* __restrict__ Qc,
                                                const unsigned short* __restrict__ Kc,
                                                const unsigned short* __restrict__ Vc,
                                                const unsigned short* __restrict__ Wt3,
                                                const float* __restrict__ bq,
                                                const float* __restrict__ bk,
                                                const float* __restrict__ bv,
                                                unsigned short* __restrict__ Qr,
                                                unsigned short* __restrict__ Kr,
                                                unsigned short* __restrict__ Vt) {
    __shared__ unsigned short As[128 * 64];
    __shared__ unsigned short Bs[128 * 64];
    const int z = blockIdx.z;
    const unsigned short* A = (z == 0) ? Qc : (z == 1) ? Kc : Vc;
    const unsigned short* Bt = Wt3 + ((size_t)z << 20);
    const float* bias = (z == 0) ? bq : (z == 1) ? bk : bv;
    const int m0 = blockIdx.y * 128, n0 = blockIdx.x * 128;

    f32x4 acc[4][4] = {};
    gemm_core128(A, Bt, As, Bs, m0, n0, acc);

    const int tid = threadIdx.x;
    const int lane = tid & 63, w = tid >> 6;
    const int wm = w & 1, wn = w >> 1;
    const int l16 = lane & 15, quad = lane >> 4;
    const float scl = (z == 0) ? QSCALE : 1.0f;

    __syncthreads();  // all waves done with K-loop LDS reads
    unsigned short* T = ((w < 2) ? As : Bs) + (w & 1) * 4096;  // per-wave 64x64
#pragma unroll
    for (int mt = 0; mt < 4; mt++)
#pragma unroll
        for (int nt = 0; nt < 4; nt++) {
            int nl = nt * 16 + l16;
            float bsv = bias[n0 + wn * 64 + nl];
#pragma unroll
            for (int r = 0; r < 4; r++) {
                int ml = mt * 16 + quad * 4 + r;
                unsigned short val = f2bf((acc[mt][nt][r] + bsv) * scl);
                int row = (z == 2) ? nl : ml;
                int col = (z == 2) ? ml : nl;
                T[row * 64 + (((col >> 3) ^ (row & 7)) * 8) + (col & 7)] = val;
            }
        }
    // same-wave RAW: compiler orders via lgkmcnt; per-wave private region
#pragma unroll
    for (int it = 0; it < 8; it++) {
        int rr = it * 8 + (lane >> 3);
        int g = lane & 7;
        us16x8 vv = *(const us16x8*)&T[rr * 64 + ((g ^ (rr & 7)) * 8)];
        if (z == 2) {
            int n = n0 + wn * 64 + rr;           // h*64+e
            int mb = m0 + wm * 64 + g * 8;
            int b = mb >> 11, s = mb & 2047;
            *(us16x8*)&Vt[(((size_t)(b * H_ + (n >> 6))) * HD_ + (n & 63)) * S_ + s] = vv;
        } else {
            unsigned short* dst = z ? Kr : Qr;
            *(us16x8*)&dst[(size_t)(m0 + wm * 64 + rr) * 1024 + n0 + wn * 64 + g * 8] = vv;
        }
    }
}

// ---------------------------------------------------------------------------
// Final: C_f32[4096][1024] = Cc * Wp^T + bp.  128x64 tile -> 512 blocks
// (2 blocks/CU: overlaps the barrier drain that 1 block/CU cannot hide).
// ---------------------------------------------------------------------------
__global__ __launch_bounds__(256) void gemm_out(const unsigned short* __restrict__ A,
                                                const unsigned short* __restrict__ Bt,
                                                const float* __restrict__ bias,
                                                float* __restrict__ C) {
    __shared__ unsigned short As[128 * 64];   // 16 KB
    __shared__ unsigned short Bs[64 * 64];    // 8 KB
    const int tid = threadIdx.x;
    const int lane = tid & 63;
    const int w = tid >> 6, wm = w & 1, wn = w >> 1;  // wn 0..1
    const int l16 = lane & 15, quad = lane >> 4;
    const int m0 = blockIdx.y * 128, n0 = blockIdx.x * 64;
    const int srow = tid >> 3;
    const int sg = (tid & 7) ^ (srow & 7);
    const unsigned short* Ag = A + (size_t)(m0 + srow) * 1024 + sg * 8;
    const unsigned short* Bg = Bt + (size_t)(n0 + srow) * 1024 + sg * 8;
    unsigned short* Al = As + tid * 8;
    unsigned short* Bl = Bs + tid * 8;
    const int xo = l16 & 7;

    f32x4 acc[4][2] = {};
    for (int k0 = 0; k0 < 1024; k0 += 64) {
        __syncthreads();
#pragma unroll
        for (int c = 0; c < 4; c++)
            glds16(Ag + (size_t)c * 32 * 1024 + k0, Al + c * 2048);
#pragma unroll
        for (int c = 0; c < 2; c++)
            glds16(Bg + (size_t)c * 32 * 1024 + k0, Bl + c * 2048);
        __syncthreads();
#pragma unroll
        for (int kc = 0; kc < 2; kc++) {
            s16x8 bf[2];
#pragma unroll
            for (int nt = 0; nt < 2; nt++)
                bf[nt] = *(const s16x8*)&Bs[(wn * 32 + nt * 16 + l16) * 64 +
                                            (((kc * 4 + quad) ^ xo) * 8)];
#pragma unroll
            for (int mt = 0; mt < 4; mt++) {
                s16x8 af = *(const s16x8*)&As[(wm * 64 + mt * 16 + l16) * 64 +
                                              (((kc * 4 + quad) ^ xo) * 8)];
#pragma unroll
                for (int nt = 0; nt < 2; nt++)
                    acc[mt][nt] = MFMA16(af, bf[nt], acc[mt][nt]);
            }
        }
    }
    const int lq = quad;
#pragma unroll
    for (int mt = 0; mt < 4; mt++)
#pragma unroll
        for (int nt = 0; nt < 2; nt++)
#pragma unroll
            for (int r = 0; r < 4; r++) {
                int mg = m0 + wm * 64 + mt * 16 + lq * 4 + r;
                int ng = n0 + wn * 32 + nt * 16 + l16;
                C[(size_t)mg * 1024 + ng] = acc[mt][nt][r] + bias[ng];
            }
}

// ---------------------------------------------------------------------------
// Flash attention v6: pipelined staging.
//  - K tile double-buffered, staged one full iteration ahead (latency hidden
//    under an entire QK+softmax+PV phase).
//  - V tile single-buffered (keeps LDS at 33.8 KB -> 4 blocks/CU), staged at
//    iteration top, consumed only after a mid-iteration counted wait
//    s_waitcnt vmcnt(2) + s_barrier: the 2 newer K-prefetch glds stay in
//    flight across the barrier (T4 counted-vmcnt discipline), V latency hides
//    under the QK+softmax phase.
//  - Issue order per iter is V-glds(2) then K-glds(2), both side-effecting
//    builtins (order preserved), so vmcnt(2) waits exactly for V.
//  - Fence+barrier pairs are single asm blocks with "memory" clobber so no
//    memory op (incl. glds builtins) migrates across them.
//  - s_setprio(1) around MFMA clusters (T5).
// Q,K row-major [B,S,D] bf16 (Q pre-scaled); V: [B,H,HD,S].
// grid: x = bh (XCD-pinned), y = q-block.
// ---------------------------------------------------------------------------
__global__ __launch_bounds__(256) void flash_attn(const unsigned short* __restrict__ Qr,
                                                  const unsigned short* __restrict__ Kr,
                                                  const unsigned short* __restrict__ Vt,
                                                  unsigned short* __restrict__ Cc) {
    __shared__ unsigned short Ks[2][64 * 64];    // [buf][key][d], double-buffered
    __shared__ unsigned short Vs[64 * 64];       // [e][s-rel], single-buffered
    constexpr int LDT = 72;
    __shared__ unsigned short P4[4][16 * LDT];   // per-wave P^T: [q][key]

    const int tid = threadIdx.x;
    const int lane = tid & 63, w = tid >> 6;
    const int l16 = lane & 15, quad = lane >> 4;
    const int bh = blockIdx.x, q0 = blockIdx.y * 64;
    const int b = bh >> 4, h = bh & 15;
    const int s_q = q0 + w * 16 + l16;           // this lane's q-row

    const unsigned short* Qp = Qr + ((size_t)(b * S_ + s_q)) * D_ + h * HD_;

    const int srow = tid >> 3;
    const int sg = (tid & 7) ^ (srow & 7);
    const unsigned short* kg = Kr + ((size_t)(b * S_ + srow)) * D_ + h * HD_ + sg * 8;
    const unsigned short* vg = Vt + (((size_t)(b * H_ + h)) * HD_ + srow) * S_ + sg * 8;
    unsigned short* Vl = Vs + tid * 8;
    unsigned short* Pw = P4[w];
    const int pbase = l16 * LDT + quad * 4;      // P store base (per-lane)
    const int xo = l16 & 7;

    // prologue: stage K tile 0 into Ks[0]
    glds16(kg, &Ks[0][tid * 8]);
    glds16(kg + (size_t)32 * D_, &Ks[0][tid * 8 + 2048]);
    kg += (size_t)64 * D_;

    s16x8 aq0 = *(const s16x8*)&Qp[quad * 8];
    s16x8 aq1 = *(const s16x8*)&Qp[32 + quad * 8];

    float l_part = 0.f;
    f32x4 o[4] = {};
    const f32x4 z4 = {0.f, 0.f, 0.f, 0.f};

    asm volatile("s_waitcnt vmcnt(0) lgkmcnt(0)\n\ts_barrier" ::: "memory");

    int cur = 0;
    for (int t = 0; t < 32; ++t) {
        const int last = (t == 31);
        // stage V(t): Vs free (all waves finished PV(t-1) before last barrier)
        glds16(vg, Vl);
        glds16(vg + (size_t)32 * S_, Vl + 2048);
        vg += 64;
        if (!last) {
            // stage K(t+1) into the other K buffer (read slot freed at iter t-1)
            unsigned short* Kn = &Ks[cur ^ 1][tid * 8];
            glds16(kg, Kn);
            glds16(kg + (size_t)32 * D_, Kn + 2048);
            kg += (size_t)64 * D_;
        }

        // scores^T on Ks[cur]: D[key][q] = K·Q^T ; keys g*16+quad*4+r, col q=l16
        const unsigned short* Kc_ = &Ks[cur][0];
        __builtin_amdgcn_s_setprio(1);
#pragma unroll
        for (int g = 0; g < 4; g++) {
            int row = g * 16 + l16;
            s16x8 kb0 = *(const s16x8*)&Kc_[row * 64 + ((quad ^ xo) * 8)];
            s16x8 kb1 = *(const s16x8*)&Kc_[row * 64 + (((4 + quad) ^ xo) * 8)];
            f32x4 sc = MFMA16(kb0, aq0, z4);
            sc = MFMA16(kb1, aq1, sc);
            float e0 = exp2f(sc[0]), e1 = exp2f(sc[1]);
            float e2 = exp2f(sc[2]), e3 = exp2f(sc[3]);
            l_part += (e0 + e1) + (e2 + e3);
            u32x2 pv;
            pv[0] = pk_bf16(e0, e1);
            pv[1] = pk_bf16(e2, e3);
            *(u32x2*)&Pw[pbase + g * 16] = pv;   // 4 contig keys, 8B store
        }
        __builtin_amdgcn_s_setprio(0);
        // P as B-operand for PV: B[k=key][n=q] = Pw[q=l16][key] (same-wave, DS in-order)
        s16x8 pB0 = *(const s16x8*)&Pw[l16 * LDT + quad * 8];
        s16x8 pB1 = *(const s16x8*)&Pw[l16 * LDT + 32 + quad * 8];

        // mid-iter: V(t) landed (leave the 2 newer K(t+1) glds in flight), all waves sync
        if (!last)
            asm volatile("s_waitcnt vmcnt(2)\n\ts_barrier" ::: "memory");
        else
            asm volatile("s_waitcnt vmcnt(0)\n\ts_barrier" ::: "memory");

        // o^T[e][q] += V^T · P^T
        __builtin_amdgcn_s_setprio(1);
#pragma unroll
        for (int tt = 0; tt < 4; tt++) {
            int row = tt * 16 + l16;
            s16x8 v0 = *(const s16x8*)&Vs[row * 64 + ((quad ^ xo) * 8)];
            s16x8 v1 = *(const s16x8*)&Vs[row * 64 + (((4 + quad) ^ xo) * 8)];
            o[tt] = MFMA16(v0, pB0, o[tt]);
            o[tt] = MFMA16(v1, pB1, o[tt]);
        }
        __builtin_amdgcn_s_setprio(0);
        // end-of-iter: my LDS reads retired (Ks[cur]/Vs safe to overwrite next iter),
        // K(t+1) landed (had a full iteration of slack)
        asm volatile("s_waitcnt vmcnt(0) lgkmcnt(0)\n\ts_barrier" ::: "memory");
        cur ^= 1;
    }

    float l = l_part;
    l += __shfl_xor(l, 16);
    l += __shfl_xor(l, 32);
    float rinv = 1.0f / l;
    unsigned short* Cp = Cc + ((size_t)(b * S_ + s_q)) * D_ + h * HD_;
#pragma unroll
    for (int t = 0; t < 4; t++) {
        u32x2 ov;
        ov[0] = pk_bf16(o[t][0] * rinv, o[t][1] * rinv);
        ov[1] = pk_bf16(o[t][2] * rinv, o[t][3] * rinv);
        *(u32x2*)&Cp[t * 16 + quad * 4] = ov;
    }
}

// ---------------------------------------------------------------------------
extern "C" void kernel_launch(void* const* d_in, const int* in_sizes, int n_in,
                              void* d_out, int out_size, void* d_ws, size_t ws_size,
                              hipStream_t stream) {
    const float* K_in = (const float*)d_in[0];
    const float* V_in = (const float*)d_in[1];
    const float* Q_in = (const float*)d_in[2];
    const float* Wk   = (const float*)d_in[3];
    const float* bk   = (const float*)d_in[4];
    const float* Wq   = (const float*)d_in[5];
    const float* bq   = (const float*)d_in[6];
    const float* Wv   = (const float*)d_in[7];
    const float* bv   = (const float*)d_in[8];
    const float* Wp   = (const float*)d_in[9];
    const float* bp   = (const float*)d_in[10];

    unsigned short* ws16 = (unsigned short*)d_ws;
    const size_t MC = 1u << 20;
    unsigned short* Qc  = ws16;            // 4M bf16 [B,S,D]
    unsigned short* Kc  = Qc + 4 * MC;
    unsigned short* Vc  = Kc + 4 * MC;
    unsigned short* Wt3 = Vc + 4 * MC;     // 3M
    unsigned short* Qr  = Wt3 + 3 * MC;    // 4M [B,S,D] projected, pre-scaled
    unsigned short* Kr  = Qr + 4 * MC;     // 4M [B,S,D]
    unsigned short* Vt  = Kr + 4 * MC;     // 4M [B,H,HD,S]
    unsigned short* Cc  = Qc;              // alias: Qc dead after gemm_qkv
    unsigned short* Wpb = Wt3;             // alias: Wt3 dead after gemm_qkv

    conv3<<<dim3(2048, 1, 3), 256, 0, stream>>>(Q_in, K_in, V_in, Qc, Kc, Vc);
    transpose_w3<<<dim3(64, 1, 3), 256, 0, stream>>>(Wq, Wk, Wv, Wt3);

    gemm_qkv<<<dim3(8, 32, 3), 256, 0, stream>>>(Qc, Kc, Vc, Wt3, bq, bk, bv, Qr, Kr, Vt);

    conv_bf16<<<512, 256, 0, stream>>>(Wp, Wpb);

    flash_attn<<<dim3(32, 32), 256, 0, stream>>>(Qr, Kr, Vt, Cc);

    gemm_out<<<dim3(16, 32), 256, 0, stream>>>(Cc, Wpb, bp, (float*)d_out);
}

// Round 2
// 259.867 us; speedup vs baseline: 1.0013x; 1.0004x over previous
//
#include <hip/hip_runtime.h>
#include <hip/hip_bf16.h>
#include <math.h>

typedef float f32x4 __attribute__((ext_vector_type(4)));
typedef short s16x8 __attribute__((ext_vector_type(8)));
typedef unsigned short us16x4 __attribute__((ext_vector_type(4)));
typedef unsigned short us16x8 __attribute__((ext_vector_type(8)));
typedef unsigned int u32x2 __attribute__((ext_vector_type(2)));

#define MFMA16(a, b, c) __builtin_amdgcn_mfma_f32_16x16x32_bf16(a, b, c, 0, 0, 0)

static constexpr int B_ = 2, S_ = 2048, D_ = 1024, H_ = 16, HD_ = 64;
// Q pre-scale: HD^-0.5 * log2(e)  -> flash softmax in exp2 domain, no max needed
static constexpr float QSCALE = 0.125f * 1.44269504088896340736f;

__device__ __forceinline__ unsigned short f2bf(float f) {
    unsigned int u = __builtin_bit_cast(unsigned int, f);
    u += 0x7fffu + ((u >> 16) & 1);  // round-to-nearest-even
    return (unsigned short)(u >> 16);
}

// packed fp32x2 -> bf16x2 (lo=a, hi=b), RNE. HW inst on gfx950.
#if defined(__has_builtin) && __has_builtin(__builtin_amdgcn_cvt_pk_bf16_f32)
typedef __bf16 bf16x2v __attribute__((ext_vector_type(2)));
__device__ __forceinline__ unsigned int pk_bf16(float a, float b) {
    return __builtin_bit_cast(unsigned int, __builtin_amdgcn_cvt_pk_bf16_f32(a, b));
}
#else
__device__ __forceinline__ unsigned int pk_bf16(float a, float b) {
    return ((unsigned int)f2bf(a)) | (((unsigned int)f2bf(b)) << 16);
}
#endif

__device__ __forceinline__ void glds16(const unsigned short* g, unsigned short* l) {
    __builtin_amdgcn_global_load_lds(
        (const __attribute__((address_space(1))) void*)g,
        (__attribute__((address_space(3))) void*)l, 16, 0, 0);
}

// ---------------------------------------------------------------------------
// fp32 -> bf16 flat converts
// ---------------------------------------------------------------------------
__global__ __launch_bounds__(256) void conv3(const float* __restrict__ s0,
                                             const float* __restrict__ s1,
                                             const float* __restrict__ s2,
                                             unsigned short* __restrict__ d0,
                                             unsigned short* __restrict__ d1,
                                             unsigned short* __restrict__ d2) {
    const int z = blockIdx.z;
    const float* src = (z == 0) ? s0 : (z == 1) ? s1 : s2;
    unsigned short* dst = (z == 0) ? d0 : (z == 1) ? d1 : d2;
    int i = (blockIdx.x * 256 + threadIdx.x) * 8;
    f32x4 a = *(const f32x4*)&src[i];
    f32x4 b = *(const f32x4*)&src[i + 4];
    s16x8 o;
#pragma unroll
    for (int j = 0; j < 4; j++) { o[j] = (short)f2bf(a[j]); o[4 + j] = (short)f2bf(b[j]); }
    *(s16x8*)&dst[i] = o;
}

__global__ __launch_bounds__(256) void conv_bf16(const float* __restrict__ src,
                                                 unsigned short* __restrict__ dst) {
    int i = (blockIdx.x * 256 + threadIdx.x) * 8;
    f32x4 a = *(const f32x4*)&src[i];
    f32x4 b = *(const f32x4*)&src[i + 4];
    s16x8 o;
#pragma unroll
    for (int j = 0; j < 4; j++) { o[j] = (short)f2bf(a[j]); o[4 + j] = (short)f2bf(b[j]); }
    *(s16x8*)&dst[i] = o;
}

// ---------------------------------------------------------------------------
// Weight transpose: Wt[(h*64+e)*1024 + d] = W[h*65536 + d*64 + e]
// ---------------------------------------------------------------------------
__global__ __launch_bounds__(256) void transpose_w3(const float* __restrict__ W0,
                                                    const float* __restrict__ W1,
                                                    const float* __restrict__ W2,
                                                    unsigned short* __restrict__ Wt3) {
    const int z = blockIdx.z;
    const float* W = (z == 0) ? W0 : (z == 1) ? W1 : W2;
    unsigned short* dst = Wt3 + ((size_t)z << 20);
    const int h = blockIdx.x >> 2, dg = blockIdx.x & 3;
    const int lane = threadIdx.x & 63, w = threadIdx.x >> 6;
    const float* Wh = W + ((size_t)h << 16);
#pragma unroll
    for (int it = 0; it < 8; it++) {
        int d0 = dg * 256 + it * 32 + w * 8;
        us16x8 o;
#pragma unroll
        for (int j = 0; j < 8; j++) o[j] = f2bf(Wh[(d0 + j) * 64 + lane]);
        *(us16x8*)&dst[(size_t)(h * 64 + lane) * 1024 + d0] = o;
    }
}

// ---------------------------------------------------------------------------
// 128x128-tile bf16 GEMM core, K=1024, BK=64, global_load_lds, XOR swizzle.
// ---------------------------------------------------------------------------
__device__ __forceinline__ void gemm_core128(const unsigned short* __restrict__ A,
                                             const unsigned short* __restrict__ Bt,
                                             unsigned short* As, unsigned short* Bs,
                                             int m0, int n0, f32x4 acc[4][4]) {
    const int tid = threadIdx.x;
    const int lane = tid & 63;
    const int w = tid >> 6, wm = w & 1, wn = w >> 1;
    const int l16 = lane & 15, quad = lane >> 4;
    const int srow = tid >> 3;
    const int sg = (tid & 7) ^ (srow & 7);
    const unsigned short* Ag = A + (size_t)(m0 + srow) * 1024 + sg * 8;
    const unsigned short* Bg = Bt + (size_t)(n0 + srow) * 1024 + sg * 8;
    unsigned short* Al = As + tid * 8;
    unsigned short* Bl = Bs + tid * 8;
    const int xo = (l16 & 7);

    for (int k0 = 0; k0 < 1024; k0 += 64) {
        __syncthreads();
#pragma unroll
        for (int c = 0; c < 4; c++) {
            glds16(Ag + (size_t)c * 32 * 1024 + k0, Al + c * 2048);
            glds16(Bg + (size_t)c * 32 * 1024 + k0, Bl + c * 2048);
        }
        __syncthreads();
#pragma unroll
        for (int kc = 0; kc < 2; kc++) {
            s16x8 bf[4];
#pragma unroll
            for (int nt = 0; nt < 4; nt++)
                bf[nt] = *(const s16x8*)&Bs[(wn * 64 + nt * 16 + l16) * 64 +
                                            (((kc * 4 + quad) ^ xo) * 8)];
#pragma unroll
            for (int mt = 0; mt < 4; mt++) {
                s16x8 af = *(const s16x8*)&As[(wm * 64 + mt * 16 + l16) * 64 +
                                              (((kc * 4 + quad) ^ xo) * 8)];
#pragma unroll
                for (int nt = 0; nt < 4; nt++)
                    acc[mt][nt] = MFMA16(af, bf[nt], acc[mt][nt]);
            }
        }
    }
}

// QKV fused via grid.z: z=0 Q -> row-major [B,S,D] (pre-scaled), z=1 K -> row-major,
// z=2 V -> transposed [B,H,HD,S]. Epilogue: per-wave LDS transpose -> 16B stores.
__global__ __launch_bounds__(256) void gemm_qkv(const unsigned short* __restrict__ Qc,
                                                const unsigned short* __restrict__ Kc,
                                                const unsigned short* __restrict__ Vc,
                                                const unsigned short* __restrict__ Wt3,
                                                const float* __restrict__ bq,
                                                const float* __restrict__ bk,
                                                const float* __restrict__ bv,
                                                unsigned short* __restrict__ Qr,
                                                unsigned short* __restrict__ Kr,
                                                unsigned short* __restrict__ Vt) {
    __shared__ unsigned short As[128 * 64];
    __shared__ unsigned short Bs[128 * 64];
    const int z = blockIdx.z;
    const unsigned short* A = (z == 0) ? Qc : (z == 1) ? Kc : Vc;
    const unsigned short* Bt = Wt3 + ((size_t)z << 20);
    const float* bias = (z == 0) ? bq : (z == 1) ? bk : bv;
    const int m0 = blockIdx.y * 128, n0 = blockIdx.x * 128;

    f32x4 acc[4][4] = {};
    gemm_core128(A, Bt, As, Bs, m0, n0, acc);

    const int tid = threadIdx.x;
    const int lane = tid & 63, w = tid >> 6;
    const int wm = w & 1, wn = w >> 1;
    const int l16 = lane & 15, quad = lane >> 4;
    const float scl = (z == 0) ? QSCALE : 1.0f;

    __syncthreads();  // all waves done with K-loop LDS reads
    unsigned short* T = ((w < 2) ? As : Bs) + (w & 1) * 4096;  // per-wave 64x64
#pragma unroll
    for (int mt = 0; mt < 4; mt++)
#pragma unroll
        for (int nt = 0; nt < 4; nt++) {
            int nl = nt * 16 + l16;
            float bsv = bias[n0 + wn * 64 + nl];
#pragma unroll
            for (int r = 0; r < 4; r++) {
                int ml = mt * 16 + quad * 4 + r;
                unsigned short val = f2bf((acc[mt][nt][r] + bsv) * scl);
                int row = (z == 2) ? nl : ml;
                int col = (z == 2) ? ml : nl;
                T[row * 64 + (((col >> 3) ^ (row & 7)) * 8) + (col & 7)] = val;
            }
        }
    // same-wave RAW: compiler orders via lgkmcnt; per-wave private region
#pragma unroll
    for (int it = 0; it < 8; it++) {
        int rr = it * 8 + (lane >> 3);
        int g = lane & 7;
        us16x8 vv = *(const us16x8*)&T[rr * 64 + ((g ^ (rr & 7)) * 8)];
        if (z == 2) {
            int n = n0 + wn * 64 + rr;           // h*64+e
            int mb = m0 + wm * 64 + g * 8;
            int b = mb >> 11, s = mb & 2047;
            *(us16x8*)&Vt[(((size_t)(b * H_ + (n >> 6))) * HD_ + (n & 63)) * S_ + s] = vv;
        } else {
            unsigned short* dst = z ? Kr : Qr;
            *(us16x8*)&dst[(size_t)(m0 + wm * 64 + rr) * 1024 + n0 + wn * 64 + g * 8] = vv;
        }
    }
}

// ---------------------------------------------------------------------------
// Final: C_f32[4096][1024] = Cc * Wp^T + bp.  128x64 tile -> 512 blocks
// ---------------------------------------------------------------------------
__global__ __launch_bounds__(256) void gemm_out(const unsigned short* __restrict__ A,
                                                const unsigned short* __restrict__ Bt,
                                                const float* __restrict__ bias,
                                                float* __restrict__ C) {
    __shared__ unsigned short As[128 * 64];   // 16 KB
    __shared__ unsigned short Bs[64 * 64];    // 8 KB
    const int tid = threadIdx.x;
    const int lane = tid & 63;
    const int w = tid >> 6, wm = w & 1, wn = w >> 1;  // wn 0..1
    const int l16 = lane & 15, quad = lane >> 4;
    const int m0 = blockIdx.y * 128, n0 = blockIdx.x * 64;
    const int srow = tid >> 3;
    const int sg = (tid & 7) ^ (srow & 7);
    const unsigned short* Ag = A + (size_t)(m0 + srow) * 1024 + sg * 8;
    const unsigned short* Bg = Bt + (size_t)(n0 + srow) * 1024 + sg * 8;
    unsigned short* Al = As + tid * 8;
    unsigned short* Bl = Bs + tid * 8;
    const int xo = l16 & 7;

    f32x4 acc[4][2] = {};
    for (int k0 = 0; k0 < 1024; k0 += 64) {
        __syncthreads();
#pragma unroll
        for (int c = 0; c < 4; c++)
            glds16(Ag + (size_t)c * 32 * 1024 + k0, Al + c * 2048);
#pragma unroll
        for (int c = 0; c < 2; c++)
            glds16(Bg + (size_t)c * 32 * 1024 + k0, Bl + c * 2048);
        __syncthreads();
#pragma unroll
        for (int kc = 0; kc < 2; kc++) {
            s16x8 bf[2];
#pragma unroll
            for (int nt = 0; nt < 2; nt++)
                bf[nt] = *(const s16x8*)&Bs[(wn * 32 + nt * 16 + l16) * 64 +
                                            (((kc * 4 + quad) ^ xo) * 8)];
#pragma unroll
            for (int mt = 0; mt < 4; mt++) {
                s16x8 af = *(const s16x8*)&As[(wm * 64 + mt * 16 + l16) * 64 +
                                              (((kc * 4 + quad) ^ xo) * 8)];
#pragma unroll
                for (int nt = 0; nt < 2; nt++)
                    acc[mt][nt] = MFMA16(af, bf[nt], acc[mt][nt]);
            }
        }
    }
    const int lq = quad;
#pragma unroll
    for (int mt = 0; mt < 4; mt++)
#pragma unroll
        for (int nt = 0; nt < 2; nt++)
#pragma unroll
            for (int r = 0; r < 4; r++) {
                int mg = m0 + wm * 64 + mt * 16 + lq * 4 + r;
                int ng = n0 + wn * 32 + nt * 16 + l16;
                C[(size_t)mg * 1024 + ng] = acc[mt][nt][r] + bias[ng];
            }
}

// ---------------------------------------------------------------------------
// Flash attention v7: key-split wave pairs + q register blocking.
//  Wave w: qh = w&1 (owns q-rows qh*32..+31 of the block's 64), kh = w>>1
//  (owns keys kh*32..+31 of each 64-key tile). Each wave reads only its
//  32-key half of K and only its key-slice of V (one b128/e-block serves
//  both q-frags: k=32 matches one MFMA), cutting LDS read traffic ~2.2x
//  vs all-waves-read-all-tiles. Q (2 frags) and O (2x4 f32x4) stay in
//  registers; partial O/l across the kh pair is reduced once through LDS
//  at the end (amortized over 32 iters).
//  K double-buffered + prefetch, V single-buffered, counted vmcnt(2) at
//  mid barrier (K prefetch stays in flight), s_setprio around MFMA.
// Q,K row-major [B,S,D] bf16 (Q pre-scaled); V: [B,H,HD,S].
// ---------------------------------------------------------------------------
__global__ __launch_bounds__(256) void flash_attn(const unsigned short* __restrict__ Qr,
                                                  const unsigned short* __restrict__ Kr,
                                                  const unsigned short* __restrict__ Vt,
                                                  unsigned short* __restrict__ Cc) {
    __shared__ unsigned short Ks[2][64 * 64];    // [buf][key][d], double-buffered, 16 KB
    __shared__ unsigned short Vs[64 * 64];       // [e][s-rel], 8 KB
    constexpr int LDT = 36;                      // P^T leading dim (shorts): odd*2 -> balanced banks
    __shared__ unsigned short P4[4][32 * LDT];   // per-wave P^T: [q 0..31][key-local 0..31], 9 KB

    const int tid = threadIdx.x;
    const int lane = tid & 63, w = tid >> 6;
    const int l16 = lane & 15, quad = lane >> 4;
    const int qh = w & 1, kh = w >> 1;
    const int bh = blockIdx.x, q0 = blockIdx.y * 64;
    const int b = bh >> 4, h = bh & 15;

    // Q fragments: 2 q-blocks of 16 rows each (q = q0 + qh*32 + qf*16 + l16)
    const unsigned short* Qp0 = Qr + ((size_t)(b * S_ + q0 + qh * 32 + l16)) * D_ + h * HD_;
    s16x8 aq[2][2];
    aq[0][0] = *(const s16x8*)&Qp0[quad * 8];
    aq[0][1] = *(const s16x8*)&Qp0[32 + quad * 8];
    aq[1][0] = *(const s16x8*)&Qp0[(size_t)16 * D_ + quad * 8];
    aq[1][1] = *(const s16x8*)&Qp0[(size_t)16 * D_ + 32 + quad * 8];

    const int srow = tid >> 3;
    const int sg = (tid & 7) ^ (srow & 7);
    const unsigned short* kg = Kr + ((size_t)(b * S_ + srow)) * D_ + h * HD_ + sg * 8;
    const unsigned short* vg = Vt + (((size_t)(b * H_ + h)) * HD_ + srow) * S_ + sg * 8;
    unsigned short* Vl = Vs + tid * 8;
    unsigned short* Pw = P4[w];
    const int xo = l16 & 7;

    // prologue: stage K tile 0 into Ks[0]
    glds16(kg, &Ks[0][tid * 8]);
    glds16(kg + (size_t)32 * D_, &Ks[0][tid * 8 + 2048]);
    kg += (size_t)64 * D_;

    float l_part[2] = {0.f, 0.f};
    f32x4 o[2][4] = {};
    const f32x4 z4 = {0.f, 0.f, 0.f, 0.f};

    asm volatile("s_waitcnt vmcnt(0) lgkmcnt(0)\n\ts_barrier" ::: "memory");

    int cur = 0;
    for (int t = 0; t < 32; ++t) {
        const int last = (t == 31);
        // stage V(t): Vs free (all waves finished PV(t-1) before last barrier)
        glds16(vg, Vl);
        glds16(vg + (size_t)32 * S_, Vl + 2048);
        vg += 64;
        if (!last) {
            // stage K(t+1) into the other K buffer
            unsigned short* Kn = &Ks[cur ^ 1][tid * 8];
            glds16(kg, Kn);
            glds16(kg + (size_t)32 * D_, Kn + 2048);
            kg += (size_t)64 * D_;
        }

        // QK^T on this wave's 32-key half: D[key][q], keys kh*32 + kg16*16 + quad*4+r
        const unsigned short* Kc_ = &Ks[cur][0];
        __builtin_amdgcn_s_setprio(1);
#pragma unroll
        for (int kg16 = 0; kg16 < 2; kg16++) {
            int row = kh * 32 + kg16 * 16 + l16;
            s16x8 kb0 = *(const s16x8*)&Kc_[row * 64 + ((quad ^ xo) * 8)];
            s16x8 kb1 = *(const s16x8*)&Kc_[row * 64 + (((4 + quad) ^ xo) * 8)];
#pragma unroll
            for (int qf = 0; qf < 2; qf++) {
                f32x4 sc = MFMA16(kb0, aq[qf][0], z4);
                sc = MFMA16(kb1, aq[qf][1], sc);
                float e0 = exp2f(sc[0]), e1 = exp2f(sc[1]);
                float e2 = exp2f(sc[2]), e3 = exp2f(sc[3]);
                l_part[qf] += (e0 + e1) + (e2 + e3);
                u32x2 pv;
                pv[0] = pk_bf16(e0, e1);
                pv[1] = pk_bf16(e2, e3);
                // P^T[q = qf*16+l16][key-local = kg16*16 + quad*4 + r]
                *(u32x2*)&Pw[(qf * 16 + l16) * LDT + kg16 * 16 + quad * 4] = pv;
            }
        }
        __builtin_amdgcn_s_setprio(0);
        // P as B-operand: B[k = key-local quad*8+j][col = q], one frag per q-block
        s16x8 pB0 = *(const s16x8*)&Pw[l16 * LDT + quad * 8];
        s16x8 pB1 = *(const s16x8*)&Pw[(16 + l16) * LDT + quad * 8];

        // mid-iter: V(t) landed (2 newer K(t+1) glds stay in flight), all waves sync
        if (!last)
            asm volatile("s_waitcnt vmcnt(2)\n\ts_barrier" ::: "memory");
        else
            asm volatile("s_waitcnt vmcnt(0)\n\ts_barrier" ::: "memory");

        // o^T[e][q] += V^T · P^T over this wave's 32 keys (k=32 = one MFMA);
        // one V read serves both q-frags.
        __builtin_amdgcn_s_setprio(1);
#pragma unroll
        for (int tt = 0; tt < 4; tt++) {
            int row = tt * 16 + l16;
            s16x8 v = *(const s16x8*)&Vs[row * 64 + (((kh * 4 + quad) ^ xo) * 8)];
            o[0][tt] = MFMA16(v, pB0, o[0][tt]);
            o[1][tt] = MFMA16(v, pB1, o[1][tt]);
        }
        __builtin_amdgcn_s_setprio(0);
        // end-of-iter: LDS reads retired, K(t+1) landed (full iteration of slack)
        asm volatile("s_waitcnt vmcnt(0) lgkmcnt(0)\n\ts_barrier" ::: "memory");
        cur ^= 1;
    }

    // ---- cross-wave (key-half) reduction: kh=1 partials -> kh=0 via LDS ----
    __syncthreads();
    float* Ored = (float*)Ks;        // [qh][e 0..63][q 0..31] f32 = 16 KB
    float* Lred = (float*)Vs;        // [qh][q 0..31]
    float lw[2];
#pragma unroll
    for (int qf = 0; qf < 2; qf++) {
        float l = l_part[qf];
        l += __shfl_xor(l, 16);
        l += __shfl_xor(l, 32);
        lw[qf] = l;
    }
    if (kh == 1) {
#pragma unroll
        for (int qf = 0; qf < 2; qf++) {
#pragma unroll
            for (int tt = 0; tt < 4; tt++)
#pragma unroll
                for (int r = 0; r < 4; r++)
                    Ored[qh * 2048 + (tt * 16 + quad * 4 + r) * 32 + qf * 16 + l16] =
                        o[qf][tt][r];
            if (quad == 0) Lred[qh * 32 + qf * 16 + l16] = lw[qf];
        }
    }
    __syncthreads();
    if (kh == 0) {
#pragma unroll
        for (int qf = 0; qf < 2; qf++) {
            float rinv = 1.0f / (lw[qf] + Lred[qh * 32 + qf * 16 + l16]);
            const int s_q = q0 + qh * 32 + qf * 16 + l16;
            unsigned short* Cp = Cc + ((size_t)(b * S_ + s_q)) * D_ + h * HD_;
#pragma unroll
            for (int tt = 0; tt < 4; tt++) {
                float s0 = o[qf][tt][0] + Ored[qh * 2048 + (tt * 16 + quad * 4 + 0) * 32 + qf * 16 + l16];
                float s1 = o[qf][tt][1] + Ored[qh * 2048 + (tt * 16 + quad * 4 + 1) * 32 + qf * 16 + l16];
                float s2 = o[qf][tt][2] + Ored[qh * 2048 + (tt * 16 + quad * 4 + 2) * 32 + qf * 16 + l16];
                float s3 = o[qf][tt][3] + Ored[qh * 2048 + (tt * 16 + quad * 4 + 3) * 32 + qf * 16 + l16];
                u32x2 ov;
                ov[0] = pk_bf16(s0 * rinv, s1 * rinv);
                ov[1] = pk_bf16(s2 * rinv, s3 * rinv);
                *(u32x2*)&Cp[tt * 16 + quad * 4] = ov;
            }
        }
    }
}

// ---------------------------------------------------------------------------
extern "C" void kernel_launch(void* const* d_in, const int* in_sizes, int n_in,
                              void* d_out, int out_size, void* d_ws, size_t ws_size,
                              hipStream_t stream) {
    const float* K_in = (const float*)d_in[0];
    const float* V_in = (const float*)d_in[1];
    const float* Q_in = (const float*)d_in[2];
    const float* Wk   = (const float*)d_in[3];
    const float* bk   = (const float*)d_in[4];
    const float* Wq   = (const float*)d_in[5];
    const float* bq   = (const float*)d_in[6];
    const float* Wv   = (const float*)d_in[7];
    const float* bv   = (const float*)d_in[8];
    const float* Wp   = (const float*)d_in[9];
    const float* bp   = (const float*)d_in[10];

    unsigned short* ws16 = (unsigned short*)d_ws;
    const size_t MC = 1u << 20;
    unsigned short* Qc  = ws16;            // 4M bf16 [B,S,D]
    unsigned short* Kc  = Qc + 4 * MC;
    unsigned short* Vc  = Kc + 4 * MC;
    unsigned short* Wt3 = Vc + 4 * MC;     // 3M
    unsigned short* Qr  = Wt3 + 3 * MC;    // 4M [B,S,D] projected, pre-scaled
    unsigned short* Kr  = Qr + 4 * MC;     // 4M [B,S,D]
    unsigned short* Vt  = Kr + 4 * MC;     // 4M [B,H,HD,S]
    unsigned short* Cc  = Qc;              // alias: Qc dead after gemm_qkv
    unsigned short* Wpb = Wt3;             // alias: Wt3 dead after gemm_qkv

    conv3<<<dim3(2048, 1, 3), 256, 0, stream>>>(Q_in, K_in, V_in, Qc, Kc, Vc);
    transpose_w3<<<dim3(64, 1, 3), 256, 0, stream>>>(Wq, Wk, Wv, Wt3);

    gemm_qkv<<<dim3(8, 32, 3), 256, 0, stream>>>(Qc, Kc, Vc, Wt3, bq, bk, bv, Qr, Kr, Vt);

    conv_bf16<<<512, 256, 0, stream>>>(Wp, Wpb);

    flash_attn<<<dim3(32, 32), 256, 0, stream>>>(Qr, Kr, Vt, Cc);

    gemm_out<<<dim3(16, 32), 256, 0, stream>>>(Cc, Wpb, bp, (float*)d_out);
}

// Round 3
// 253.750 us; speedup vs baseline: 1.0255x; 1.0241x over previous
//
#include <hip/hip_runtime.h>
#include <hip/hip_bf16.h>
#include <math.h>

typedef float f32x4 __attribute__((ext_vector_type(4)));
typedef short s16x8 __attribute__((ext_vector_type(8)));
typedef unsigned short us16x4 __attribute__((ext_vector_type(4)));
typedef unsigned short us16x8 __attribute__((ext_vector_type(8)));
typedef unsigned int u32x2 __attribute__((ext_vector_type(2)));

#define MFMA16(a, b, c) __builtin_amdgcn_mfma_f32_16x16x32_bf16(a, b, c, 0, 0, 0)

static constexpr int B_ = 2, S_ = 2048, D_ = 1024, H_ = 16, HD_ = 64;
// Q pre-scale: HD^-0.5 * log2(e)  -> flash softmax in exp2 domain, no max needed
static constexpr float QSCALE = 0.125f * 1.44269504088896340736f;

__device__ __forceinline__ unsigned short f2bf(float f) {
    unsigned int u = __builtin_bit_cast(unsigned int, f);
    u += 0x7fffu + ((u >> 16) & 1);  // round-to-nearest-even
    return (unsigned short)(u >> 16);
}

// packed fp32x2 -> bf16x2 (lo=a, hi=b), RNE. HW inst on gfx950.
#if defined(__has_builtin) && __has_builtin(__builtin_amdgcn_cvt_pk_bf16_f32)
typedef __bf16 bf16x2v __attribute__((ext_vector_type(2)));
__device__ __forceinline__ unsigned int pk_bf16(float a, float b) {
    return __builtin_bit_cast(unsigned int, __builtin_amdgcn_cvt_pk_bf16_f32(a, b));
}
#else
__device__ __forceinline__ unsigned int pk_bf16(float a, float b) {
    return ((unsigned int)f2bf(a)) | (((unsigned int)f2bf(b)) << 16);
}
#endif

__device__ __forceinline__ void glds16(const unsigned short* g, unsigned short* l) {
    __builtin_amdgcn_global_load_lds(
        (const __attribute__((address_space(1))) void*)g,
        (__attribute__((address_space(3))) void*)l, 16, 0, 0);
}

// ---------------------------------------------------------------------------
// fp32 -> bf16 flat converts
// ---------------------------------------------------------------------------
__global__ __launch_bounds__(256) void conv3(const float* __restrict__ s0,
                                             const float* __restrict__ s1,
                                             const float* __restrict__ s2,
                                             unsigned short* __restrict__ d0,
                                             unsigned short* __restrict__ d1,
                                             unsigned short* __restrict__ d2) {
    const int z = blockIdx.z;
    const float* src = (z == 0) ? s0 : (z == 1) ? s1 : s2;
    unsigned short* dst = (z == 0) ? d0 : (z == 1) ? d1 : d2;
    int i = (blockIdx.x * 256 + threadIdx.x) * 8;
    f32x4 a = *(const f32x4*)&src[i];
    f32x4 b = *(const f32x4*)&src[i + 4];
    s16x8 o;
#pragma unroll
    for (int j = 0; j < 4; j++) { o[j] = (short)f2bf(a[j]); o[4 + j] = (short)f2bf(b[j]); }
    *(s16x8*)&dst[i] = o;
}

__global__ __launch_bounds__(256) void conv_bf16(const float* __restrict__ src,
                                                 unsigned short* __restrict__ dst) {
    int i = (blockIdx.x * 256 + threadIdx.x) * 8;
    f32x4 a = *(const f32x4*)&src[i];
    f32x4 b = *(const f32x4*)&src[i + 4];
    s16x8 o;
#pragma unroll
    for (int j = 0; j < 4; j++) { o[j] = (short)f2bf(a[j]); o[4 + j] = (short)f2bf(b[j]); }
    *(s16x8*)&dst[i] = o;
}

// ---------------------------------------------------------------------------
// Weight transpose: Wt[(h*64+e)*1024 + d] = W[h*65536 + d*64 + e]
// ---------------------------------------------------------------------------
__global__ __launch_bounds__(256) void transpose_w3(const float* __restrict__ W0,
                                                    const float* __restrict__ W1,
                                                    const float* __restrict__ W2,
                                                    unsigned short* __restrict__ Wt3) {
    const int z = blockIdx.z;
    const float* W = (z == 0) ? W0 : (z == 1) ? W1 : W2;
    unsigned short* dst = Wt3 + ((size_t)z << 20);
    const int h = blockIdx.x >> 2, dg = blockIdx.x & 3;
    const int lane = threadIdx.x & 63, w = threadIdx.x >> 6;
    const float* Wh = W + ((size_t)h << 16);
#pragma unroll
    for (int it = 0; it < 8; it++) {
        int d0 = dg * 256 + it * 32 + w * 8;
        us16x8 o;
#pragma unroll
        for (int j = 0; j < 8; j++) o[j] = f2bf(Wh[(d0 + j) * 64 + lane]);
        *(us16x8*)&dst[(size_t)(h * 64 + lane) * 1024 + d0] = o;
    }
}

// ---------------------------------------------------------------------------
// 128x128-tile bf16 GEMM core, K=1024, BK=64, global_load_lds, XOR swizzle.
// ---------------------------------------------------------------------------
__device__ __forceinline__ void gemm_core128(const unsigned short* __restrict__ A,
                                             const unsigned short* __restrict__ Bt,
                                             unsigned short* As, unsigned short* Bs,
                                             int m0, int n0, f32x4 acc[4][4]) {
    const int tid = threadIdx.x;
    const int lane = tid & 63;
    const int w = tid >> 6, wm = w & 1, wn = w >> 1;
    const int l16 = lane & 15, quad = lane >> 4;
    const int srow = tid >> 3;
    const int sg = (tid & 7) ^ (srow & 7);
    const unsigned short* Ag = A + (size_t)(m0 + srow) * 1024 + sg * 8;
    const unsigned short* Bg = Bt + (size_t)(n0 + srow) * 1024 + sg * 8;
    unsigned short* Al = As + tid * 8;
    unsigned short* Bl = Bs + tid * 8;
    const int xo = (l16 & 7);

    for (int k0 = 0; k0 < 1024; k0 += 64) {
        __syncthreads();
#pragma unroll
        for (int c = 0; c < 4; c++) {
            glds16(Ag + (size_t)c * 32 * 1024 + k0, Al + c * 2048);
            glds16(Bg + (size_t)c * 32 * 1024 + k0, Bl + c * 2048);
        }
        __syncthreads();
#pragma unroll
        for (int kc = 0; kc < 2; kc++) {
            s16x8 bf[4];
#pragma unroll
            for (int nt = 0; nt < 4; nt++)
                bf[nt] = *(const s16x8*)&Bs[(wn * 64 + nt * 16 + l16) * 64 +
                                            (((kc * 4 + quad) ^ xo) * 8)];
#pragma unroll
            for (int mt = 0; mt < 4; mt++) {
                s16x8 af = *(const s16x8*)&As[(wm * 64 + mt * 16 + l16) * 64 +
                                              (((kc * 4 + quad) ^ xo) * 8)];
#pragma unroll
                for (int nt = 0; nt < 4; nt++)
                    acc[mt][nt] = MFMA16(af, bf[nt], acc[mt][nt]);
            }
        }
    }
}

// QKV fused via grid.z: z=0 Q -> row-major [B,S,D] (pre-scaled), z=1 K -> row-major,
// z=2 V -> transposed [B,H,HD,S]. Epilogue: per-wave LDS transpose -> 16B stores.
// XCD-chunked bijective swizzle (T1): 768 blocks, 96/XCD; contiguous work ids
// share A row-panels -> panel re-reads become same-XCD L2 hits.
__global__ __launch_bounds__(256) void gemm_qkv(const unsigned short* __restrict__ Qc,
                                                const unsigned short* __restrict__ Kc,
                                                const unsigned short* __restrict__ Vc,
                                                const unsigned short* __restrict__ Wt3,
                                                const float* __restrict__ bq,
                                                const float* __restrict__ bk,
                                                const float* __restrict__ bv,
                                                unsigned short* __restrict__ Qr,
                                                unsigned short* __restrict__ Kr,
                                                unsigned short* __restrict__ Vt) {
    __shared__ unsigned short As[128 * 64];
    __shared__ unsigned short Bs[128 * 64];
    // flat hw id (x fastest) -> XCD-chunked work id
    const int flat = blockIdx.x + (blockIdx.y << 3) + (blockIdx.z << 8);  // 0..767
    const int wid = (flat & 7) * 96 + (flat >> 3);                        // bijective (768%8==0)
    const int z = wid >> 8;
    const int by = (wid & 255) >> 3;
    const int bx = wid & 7;
    const unsigned short* A = (z == 0) ? Qc : (z == 1) ? Kc : Vc;
    const unsigned short* Bt = Wt3 + ((size_t)z << 20);
    const float* bias = (z == 0) ? bq : (z == 1) ? bk : bv;
    const int m0 = by * 128, n0 = bx * 128;

    f32x4 acc[4][4] = {};
    gemm_core128(A, Bt, As, Bs, m0, n0, acc);

    const int tid = threadIdx.x;
    const int lane = tid & 63, w = tid >> 6;
    const int wm = w & 1, wn = w >> 1;
    const int l16 = lane & 15, quad = lane >> 4;
    const float scl = (z == 0) ? QSCALE : 1.0f;

    __syncthreads();  // all waves done with K-loop LDS reads
    unsigned short* T = ((w < 2) ? As : Bs) + (w & 1) * 4096;  // per-wave 64x64
#pragma unroll
    for (int mt = 0; mt < 4; mt++)
#pragma unroll
        for (int nt = 0; nt < 4; nt++) {
            int nl = nt * 16 + l16;
            float bsv = bias[n0 + wn * 64 + nl];
#pragma unroll
            for (int r = 0; r < 4; r++) {
                int ml = mt * 16 + quad * 4 + r;
                unsigned short val = f2bf((acc[mt][nt][r] + bsv) * scl);
                int row = (z == 2) ? nl : ml;
                int col = (z == 2) ? ml : nl;
                T[row * 64 + (((col >> 3) ^ (row & 7)) * 8) + (col & 7)] = val;
            }
        }
    // same-wave RAW: compiler orders via lgkmcnt; per-wave private region
#pragma unroll
    for (int it = 0; it < 8; it++) {
        int rr = it * 8 + (lane >> 3);
        int g = lane & 7;
        us16x8 vv = *(const us16x8*)&T[rr * 64 + ((g ^ (rr & 7)) * 8)];
        if (z == 2) {
            int n = n0 + wn * 64 + rr;           // h*64+e
            int mb = m0 + wm * 64 + g * 8;
            int b = mb >> 11, s = mb & 2047;
            *(us16x8*)&Vt[(((size_t)(b * H_ + (n >> 6))) * HD_ + (n & 63)) * S_ + s] = vv;
        } else {
            unsigned short* dst = z ? Kr : Qr;
            *(us16x8*)&dst[(size_t)(m0 + wm * 64 + rr) * 1024 + n0 + wn * 64 + g * 8] = vv;
        }
    }
}

// ---------------------------------------------------------------------------
// Final: C_f32[4096][1024] = Cc * Wp^T + bp.  128x64 tile -> 512 blocks
// (2 blocks/CU). XCD-chunked swizzle: 64 contiguous work ids per XCD ->
// 4 A-panels/XCD (1 MB) re-read 16x from L2 instead of HBM.
// ---------------------------------------------------------------------------
__global__ __launch_bounds__(256) void gemm_out(const unsigned short* __restrict__ A,
                                                const unsigned short* __restrict__ Bt,
                                                const float* __restrict__ bias,
                                                float* __restrict__ C) {
    __shared__ unsigned short As[128 * 64];   // 16 KB
    __shared__ unsigned short Bs[64 * 64];    // 8 KB
    const int tid = threadIdx.x;
    const int lane = tid & 63;
    const int w = tid >> 6, wm = w & 1, wn = w >> 1;  // wn 0..1
    const int l16 = lane & 15, quad = lane >> 4;
    const int flat = blockIdx.x + (blockIdx.y << 4);  // 0..511
    const int wid = (flat & 7) * 64 + (flat >> 3);    // bijective (512%8==0)
    const int m0 = (wid >> 4) * 128, n0 = (wid & 15) * 64;
    const int srow = tid >> 3;
    const int sg = (tid & 7) ^ (srow & 7);
    const unsigned short* Ag = A + (size_t)(m0 + srow) * 1024 + sg * 8;
    const unsigned short* Bg = Bt + (size_t)(n0 + srow) * 1024 + sg * 8;
    unsigned short* Al = As + tid * 8;
    unsigned short* Bl = Bs + tid * 8;
    const int xo = l16 & 7;

    f32x4 acc[4][2] = {};
    for (int k0 = 0; k0 < 1024; k0 += 64) {
        __syncthreads();
#pragma unroll
        for (int c = 0; c < 4; c++)
            glds16(Ag + (size_t)c * 32 * 1024 + k0, Al + c * 2048);
#pragma unroll
        for (int c = 0; c < 2; c++)
            glds16(Bg + (size_t)c * 32 * 1024 + k0, Bl + c * 2048);
        __syncthreads();
#pragma unroll
        for (int kc = 0; kc < 2; kc++) {
            s16x8 bf[2];
#pragma unroll
            for (int nt = 0; nt < 2; nt++)
                bf[nt] = *(const s16x8*)&Bs[(wn * 32 + nt * 16 + l16) * 64 +
                                            (((kc * 4 + quad) ^ xo) * 8)];
#pragma unroll
            for (int mt = 0; mt < 4; mt++) {
                s16x8 af = *(const s16x8*)&As[(wm * 64 + mt * 16 + l16) * 64 +
                                              (((kc * 4 + quad) ^ xo) * 8)];
#pragma unroll
                for (int nt = 0; nt < 2; nt++)
                    acc[mt][nt] = MFMA16(af, bf[nt], acc[mt][nt]);
            }
        }
    }
    const int lq = quad;
#pragma unroll
    for (int mt = 0; mt < 4; mt++)
#pragma unroll
        for (int nt = 0; nt < 2; nt++)
#pragma unroll
            for (int r = 0; r < 4; r++) {
                int mg = m0 + wm * 64 + mt * 16 + lq * 4 + r;
                int ng = n0 + wn * 32 + nt * 16 + l16;
                C[(size_t)mg * 1024 + ng] = acc[mt][nt][r] + bias[ng];
            }
}

// ---------------------------------------------------------------------------
// Flash attention v6 (best measured): pipelined staging.
//  K double-buffered + 1-iter-ahead prefetch; V single-buffered with counted
//  vmcnt(2) mid-barrier (K prefetch stays in flight); s_setprio around MFMA.
// Q,K row-major [B,S,D] bf16 (Q pre-scaled); V: [B,H,HD,S].
// grid: x = bh (all q-blocks of a head land on one XCD), y = q-block.
// ---------------------------------------------------------------------------
__global__ __launch_bounds__(256) void flash_attn(const unsigned short* __restrict__ Qr,
                                                  const unsigned short* __restrict__ Kr,
                                                  const unsigned short* __restrict__ Vt,
                                                  unsigned short* __restrict__ Cc) {
    __shared__ unsigned short Ks[2][64 * 64];    // [buf][key][d], double-buffered
    __shared__ unsigned short Vs[64 * 64];       // [e][s-rel], single-buffered
    constexpr int LDT = 72;
    __shared__ unsigned short P4[4][16 * LDT];   // per-wave P^T: [q][key]

    const int tid = threadIdx.x;
    const int lane = tid & 63, w = tid >> 6;
    const int l16 = lane & 15, quad = lane >> 4;
    const int bh = blockIdx.x, q0 = blockIdx.y * 64;
    const int b = bh >> 4, h = bh & 15;
    const int s_q = q0 + w * 16 + l16;           // this lane's q-row

    const unsigned short* Qp = Qr + ((size_t)(b * S_ + s_q)) * D_ + h * HD_;

    const int srow = tid >> 3;
    const int sg = (tid & 7) ^ (srow & 7);
    const unsigned short* kg = Kr + ((size_t)(b * S_ + srow)) * D_ + h * HD_ + sg * 8;
    const unsigned short* vg = Vt + (((size_t)(b * H_ + h)) * HD_ + srow) * S_ + sg * 8;
    unsigned short* Vl = Vs + tid * 8;
    unsigned short* Pw = P4[w];
    const int pbase = l16 * LDT + quad * 4;      // P store base (per-lane)
    const int xo = l16 & 7;

    // prologue: stage K tile 0 into Ks[0]
    glds16(kg, &Ks[0][tid * 8]);
    glds16(kg + (size_t)32 * D_, &Ks[0][tid * 8 + 2048]);
    kg += (size_t)64 * D_;

    s16x8 aq0 = *(const s16x8*)&Qp[quad * 8];
    s16x8 aq1 = *(const s16x8*)&Qp[32 + quad * 8];

    float l_part = 0.f;
    f32x4 o[4] = {};
    const f32x4 z4 = {0.f, 0.f, 0.f, 0.f};

    asm volatile("s_waitcnt vmcnt(0) lgkmcnt(0)\n\ts_barrier" ::: "memory");

    int cur = 0;
    for (int t = 0; t < 32; ++t) {
        const int last = (t == 31);
        // stage V(t): Vs free (all waves finished PV(t-1) before last barrier)
        glds16(vg, Vl);
        glds16(vg + (size_t)32 * S_, Vl + 2048);
        vg += 64;
        if (!last) {
            // stage K(t+1) into the other K buffer (read slot freed at iter t-1)
            unsigned short* Kn = &Ks[cur ^ 1][tid * 8];
            glds16(kg, Kn);
            glds16(kg + (size_t)32 * D_, Kn + 2048);
            kg += (size_t)64 * D_;
        }

        // scores^T on Ks[cur]: D[key][q] = K·Q^T ; keys g*16+quad*4+r, col q=l16
        const unsigned short* Kc_ = &Ks[cur][0];
        __builtin_amdgcn_s_setprio(1);
#pragma unroll
        for (int g = 0; g < 4; g++) {
            int row = g * 16 + l16;
            s16x8 kb0 = *(const s16x8*)&Kc_[row * 64 + ((quad ^ xo) * 8)];
            s16x8 kb1 = *(const s16x8*)&Kc_[row * 64 + (((4 + quad) ^ xo) * 8)];
            f32x4 sc = MFMA16(kb0, aq0, z4);
            sc = MFMA16(kb1, aq1, sc);
            float e0 = exp2f(sc[0]), e1 = exp2f(sc[1]);
            float e2 = exp2f(sc[2]), e3 = exp2f(sc[3]);
            l_part += (e0 + e1) + (e2 + e3);
            u32x2 pv;
            pv[0] = pk_bf16(e0, e1);
            pv[1] = pk_bf16(e2, e3);
            *(u32x2*)&Pw[pbase + g * 16] = pv;   // 4 contig keys, 8B store
        }
        __builtin_amdgcn_s_setprio(0);
        // P as B-operand for PV: B[k=key][n=q] = Pw[q=l16][key] (same-wave, DS in-order)
        s16x8 pB0 = *(const s16x8*)&Pw[l16 * LDT + quad * 8];
        s16x8 pB1 = *(const s16x8*)&Pw[l16 * LDT + 32 + quad * 8];

        // mid-iter: V(t) landed (leave the 2 newer K(t+1) glds in flight), all waves sync
        if (!last)
            asm volatile("s_waitcnt vmcnt(2)\n\ts_barrier" ::: "memory");
        else
            asm volatile("s_waitcnt vmcnt(0)\n\ts_barrier" ::: "memory");

        // o^T[e][q] += V^T · P^T
        __builtin_amdgcn_s_setprio(1);
#pragma unroll
        for (int tt = 0; tt < 4; tt++) {
            int row = tt * 16 + l16;
            s16x8 v0 = *(const s16x8*)&Vs[row * 64 + ((quad ^ xo) * 8)];
            s16x8 v1 = *(const s16x8*)&Vs[row * 64 + (((4 + quad) ^ xo) * 8)];
            o[tt] = MFMA16(v0, pB0, o[tt]);
            o[tt] = MFMA16(v1, pB1, o[tt]);
        }
        __builtin_amdgcn_s_setprio(0);
        // end-of-iter: my LDS reads retired (Ks[cur]/Vs safe to overwrite next iter),
        // K(t+1) landed (had a full iteration of slack)
        asm volatile("s_waitcnt vmcnt(0) lgkmcnt(0)\n\ts_barrier" ::: "memory");
        cur ^= 1;
    }

    float l = l_part;
    l += __shfl_xor(l, 16);
    l += __shfl_xor(l, 32);
    float rinv = 1.0f / l;
    unsigned short* Cp = Cc + ((size_t)(b * S_ + s_q)) * D_ + h * HD_;
#pragma unroll
    for (int t = 0; t < 4; t++) {
        u32x2 ov;
        ov[0] = pk_bf16(o[t][0] * rinv, o[t][1] * rinv);
        ov[1] = pk_bf16(o[t][2] * rinv, o[t][3] * rinv);
        *(u32x2*)&Cp[t * 16 + quad * 4] = ov;
    }
}

// ---------------------------------------------------------------------------
extern "C" void kernel_launch(void* const* d_in, const int* in_sizes, int n_in,
                              void* d_out, int out_size, void* d_ws, size_t ws_size,
                              hipStream_t stream) {
    const float* K_in = (const float*)d_in[0];
    const float* V_in = (const float*)d_in[1];
    const float* Q_in = (const float*)d_in[2];
    const float* Wk   = (const float*)d_in[3];
    const float* bk   = (const float*)d_in[4];
    const float* Wq   = (const float*)d_in[5];
    const float* bq   = (const float*)d_in[6];
    const float* Wv   = (const float*)d_in[7];
    const float* bv   = (const float*)d_in[8];
    const float* Wp   = (const float*)d_in[9];
    const float* bp   = (const float*)d_in[10];

    unsigned short* ws16 = (unsigned short*)d_ws;
    const size_t MC = 1u << 20;
    unsigned short* Qc  = ws16;            // 4M bf16 [B,S,D]
    unsigned short* Kc  = Qc + 4 * MC;
    unsigned short* Vc  = Kc + 4 * MC;
    unsigned short* Wt3 = Vc + 4 * MC;     // 3M
    unsigned short* Qr  = Wt3 + 3 * MC;    // 4M [B,S,D] projected, pre-scaled
    unsigned short* Kr  = Qr + 4 * MC;     // 4M [B,S,D]
    unsigned short* Vt  = Kr + 4 * MC;     // 4M [B,H,HD,S]
    unsigned short* Cc  = Qc;              // alias: Qc dead after gemm_qkv
    unsigned short* Wpb = Wt3;             // alias: Wt3 dead after gemm_qkv

    conv3<<<dim3(2048, 1, 3), 256, 0, stream>>>(Q_in, K_in, V_in, Qc, Kc, Vc);
    transpose_w3<<<dim3(64, 1, 3), 256, 0, stream>>>(Wq, Wk, Wv, Wt3);

    gemm_qkv<<<dim3(8, 32, 3), 256, 0, stream>>>(Qc, Kc, Vc, Wt3, bq, bk, bv, Qr, Kr, Vt);

    conv_bf16<<<512, 256, 0, stream>>>(Wp, Wpb);

    flash_attn<<<dim3(32, 32), 256, 0, stream>>>(Qr, Kr, Vt, Cc);

    gemm_out<<<dim3(16, 32), 256, 0, stream>>>(Cc, Wpb, bp, (float*)d_out);
}

// Round 4
// 253.327 us; speedup vs baseline: 1.0272x; 1.0017x over previous
//
#include <hip/hip_runtime.h>
#include <hip/hip_bf16.h>
#include <math.h>

typedef float f32x4 __attribute__((ext_vector_type(4)));
typedef short s16x8 __attribute__((ext_vector_type(8)));
typedef unsigned short us16x4 __attribute__((ext_vector_type(4)));
typedef unsigned short us16x8 __attribute__((ext_vector_type(8)));
typedef unsigned int u32x2 __attribute__((ext_vector_type(2)));

#define MFMA16(a, b, c) __builtin_amdgcn_mfma_f32_16x16x32_bf16(a, b, c, 0, 0, 0)

static constexpr int B_ = 2, S_ = 2048, D_ = 1024, H_ = 16, HD_ = 64;
// Q pre-scale: HD^-0.5 * log2(e)  -> flash softmax in exp2 domain, no max needed
static constexpr float QSCALE = 0.125f * 1.44269504088896340736f;

__device__ __forceinline__ unsigned short f2bf(float f) {
    unsigned int u = __builtin_bit_cast(unsigned int, f);
    u += 0x7fffu + ((u >> 16) & 1);  // round-to-nearest-even
    return (unsigned short)(u >> 16);
}

// packed fp32x2 -> bf16x2 (lo=a, hi=b), RNE. HW inst on gfx950.
#if defined(__has_builtin) && __has_builtin(__builtin_amdgcn_cvt_pk_bf16_f32)
typedef __bf16 bf16x2v __attribute__((ext_vector_type(2)));
__device__ __forceinline__ unsigned int pk_bf16(float a, float b) {
    return __builtin_bit_cast(unsigned int, __builtin_amdgcn_cvt_pk_bf16_f32(a, b));
}
#else
__device__ __forceinline__ unsigned int pk_bf16(float a, float b) {
    return ((unsigned int)f2bf(a)) | (((unsigned int)f2bf(b)) << 16);
}
#endif

__device__ __forceinline__ void glds16(const unsigned short* g, unsigned short* l) {
    __builtin_amdgcn_global_load_lds(
        (const __attribute__((address_space(1))) void*)g,
        (__attribute__((address_space(3))) void*)l, 16, 0, 0);
}

__device__ __forceinline__ void glds16f(const float* g, float* l) {
    __builtin_amdgcn_global_load_lds(
        (const __attribute__((address_space(1))) void*)g,
        (__attribute__((address_space(3))) void*)l, 16, 0, 0);
}

// ---------------------------------------------------------------------------
// Weight transpose: Wt[(h*64+e)*1024 + d] = W[h*65536 + d*64 + e]
// ---------------------------------------------------------------------------
__global__ __launch_bounds__(256) void transpose_w3(const float* __restrict__ W0,
                                                    const float* __restrict__ W1,
                                                    const float* __restrict__ W2,
                                                    unsigned short* __restrict__ Wt3) {
    const int z = blockIdx.z;
    const float* W = (z == 0) ? W0 : (z == 1) ? W1 : W2;
    unsigned short* dst = Wt3 + ((size_t)z << 20);
    const int h = blockIdx.x >> 2, dg = blockIdx.x & 3;
    const int lane = threadIdx.x & 63, w = threadIdx.x >> 6;
    const float* Wh = W + ((size_t)h << 16);
#pragma unroll
    for (int it = 0; it < 8; it++) {
        int d0 = dg * 256 + it * 32 + w * 8;
        us16x8 o;
#pragma unroll
        for (int j = 0; j < 8; j++) o[j] = f2bf(Wh[(d0 + j) * 64 + lane]);
        *(us16x8*)&dst[(size_t)(h * 64 + lane) * 1024 + d0] = o;
    }
}

// ---------------------------------------------------------------------------
// QKV projection GEMM, A staged directly from f32 inputs (conv3 eliminated).
// A-tile: [128 rows][64 k] f32 in LDS (32 KB), 16-granule/row XOR swizzle
//   (granule = 16B = 4 floats): LDS[row][p] = global[row][p ^ (row&15)],
//   staged linear-dest (rule #21) with inverse-swizzled source, read with
//   p = u ^ (row&15); bf16 fragments built in-register via cvt_pk (RNE,
//   bit-identical to the old conv3 path).
// B-tile: bf16 weights (transpose_w3 output), unchanged 8-granule swizzle.
// z=0 Q -> row-major [B,S,D] (pre-scaled), z=1 K -> row-major,
// z=2 V -> transposed [B,H,HD,S]. XCD-chunked bijective swizzle (T1).
// ---------------------------------------------------------------------------
__global__ __launch_bounds__(256) void gemm_qkv(const float* __restrict__ Qf,
                                                const float* __restrict__ Kf,
                                                const float* __restrict__ Vf,
                                                const unsigned short* __restrict__ Wt3,
                                                const float* __restrict__ bq,
                                                const float* __restrict__ bk,
                                                const float* __restrict__ bv,
                                                unsigned short* __restrict__ Qr,
                                                unsigned short* __restrict__ Kr,
                                                unsigned short* __restrict__ Vt) {
    __shared__ float Asf[128 * 64];           // 32 KB (f32 A tile)
    __shared__ unsigned short Bs[128 * 64];   // 16 KB (bf16 B tile)
    // flat hw id (x fastest) -> XCD-chunked work id
    const int flat = blockIdx.x + (blockIdx.y << 3) + (blockIdx.z << 8);  // 0..767
    const int wid = (flat & 7) * 96 + (flat >> 3);                        // bijective (768%8==0)
    const int z = wid >> 8;
    const int by = (wid & 255) >> 3;
    const int bx = wid & 7;
    const float* A = (z == 0) ? Qf : (z == 1) ? Kf : Vf;
    const float* bias = (z == 0) ? bq : (z == 1) ? bk : bv;
    const int m0 = by * 128, n0 = bx * 128;

    const int tid = threadIdx.x;
    const int lane = tid & 63;
    const int w = tid >> 6, wm = w & 1, wn = w >> 1;
    const int l16 = lane & 15, quad = lane >> 4;
    // A staging: 16 rows/round, granule su = (tid&15) ^ (row&15), row&15 = tid>>4
    const int arow = tid >> 4;
    const int su = (tid & 15) ^ arow;
    const float* Ag = A + (size_t)(m0 + arow) * 1024 + su * 4;
    float* Alf = Asf + tid * 4;
    // B staging: 32 rows/round, unchanged
    const int srow = tid >> 3;
    const int sg = (tid & 7) ^ (srow & 7);
    const unsigned short* Bg = Wt3 + ((size_t)z << 20) + (size_t)(n0 + srow) * 1024 + sg * 8;
    unsigned short* Bl = Bs + tid * 8;
    const int xo8 = l16 & 7;

    f32x4 acc[4][4] = {};
    for (int k0 = 0; k0 < 1024; k0 += 64) {
        __syncthreads();
#pragma unroll
        for (int c = 0; c < 8; c++)
            glds16f(Ag + (size_t)c * 16 * 1024 + k0, Alf + c * 1024);
#pragma unroll
        for (int c = 0; c < 4; c++)
            glds16(Bg + (size_t)c * 32 * 1024 + k0, Bl + c * 2048);
        __syncthreads();
#pragma unroll
        for (int kc = 0; kc < 2; kc++) {
            s16x8 bf[4];
#pragma unroll
            for (int nt = 0; nt < 4; nt++)
                bf[nt] = *(const s16x8*)&Bs[(wn * 64 + nt * 16 + l16) * 64 +
                                            (((kc * 4 + quad) ^ xo8) * 8)];
#pragma unroll
            for (int mt = 0; mt < 4; mt++) {
                const int row = wm * 64 + mt * 16 + l16;
                const int u = kc * 8 + quad * 2;
                const int e = row & 15;
                f32x4 lo = *(const f32x4*)&Asf[row * 64 + ((u ^ e) * 4)];
                f32x4 hi = *(const f32x4*)&Asf[row * 64 + (((u + 1) ^ e) * 4)];
                s16x8 af;
                ((unsigned int*)&af)[0] = pk_bf16(lo[0], lo[1]);
                ((unsigned int*)&af)[1] = pk_bf16(lo[2], lo[3]);
                ((unsigned int*)&af)[2] = pk_bf16(hi[0], hi[1]);
                ((unsigned int*)&af)[3] = pk_bf16(hi[2], hi[3]);
#pragma unroll
                for (int nt = 0; nt < 4; nt++)
                    acc[mt][nt] = MFMA16(af, bf[nt], acc[mt][nt]);
            }
        }
    }

    const float scl = (z == 0) ? QSCALE : 1.0f;

    __syncthreads();  // all waves done with K-loop LDS reads
    unsigned short* T = ((unsigned short*)Asf) + w * 4096;  // per-wave 64x64 in Asf (32 KB)
#pragma unroll
    for (int mt = 0; mt < 4; mt++)
#pragma unroll
        for (int nt = 0; nt < 4; nt++) {
            int nl = nt * 16 + l16;
            float bsv = bias[n0 + wn * 64 + nl];
#pragma unroll
            for (int r = 0; r < 4; r++) {
                int ml = mt * 16 + quad * 4 + r;
                unsigned short val = f2bf((acc[mt][nt][r] + bsv) * scl);
                int row = (z == 2) ? nl : ml;
                int col = (z == 2) ? ml : nl;
                T[row * 64 + (((col >> 3) ^ (row & 7)) * 8) + (col & 7)] = val;
            }
        }
    // same-wave RAW: compiler orders via lgkmcnt; per-wave private region
#pragma unroll
    for (int it = 0; it < 8; it++) {
        int rr = it * 8 + (lane >> 3);
        int g = lane & 7;
        us16x8 vv = *(const us16x8*)&T[rr * 64 + ((g ^ (rr & 7)) * 8)];
        if (z == 2) {
            int n = n0 + wn * 64 + rr;           // h*64+e
            int mb = m0 + wm * 64 + g * 8;
            int b = mb >> 11, s = mb & 2047;
            *(us16x8*)&Vt[(((size_t)(b * H_ + (n >> 6))) * HD_ + (n & 63)) * S_ + s] = vv;
        } else {
            unsigned short* dst = z ? Kr : Qr;
            *(us16x8*)&dst[(size_t)(m0 + wm * 64 + rr) * 1024 + n0 + wn * 64 + g * 8] = vv;
        }
    }
}

// ---------------------------------------------------------------------------
// Final: C_f32[4096][1024] = Cc * Wp^T + bp.  128x64 tile -> 512 blocks
// (2 blocks/CU). B (Wp) staged directly from f32 (conv_bf16 eliminated),
// same 16-granule XOR scheme as gemm_qkv's A. A (Cc) stays bf16.
// XCD-chunked swizzle.
// ---------------------------------------------------------------------------
__global__ __launch_bounds__(256) void gemm_out(const unsigned short* __restrict__ A,
                                                const float* __restrict__ Wp,
                                                const float* __restrict__ bias,
                                                float* __restrict__ C) {
    __shared__ unsigned short As[128 * 64];   // 16 KB (bf16 A tile)
    __shared__ float Bsf[64 * 64];            // 16 KB (f32 B tile)
    const int tid = threadIdx.x;
    const int lane = tid & 63;
    const int w = tid >> 6, wm = w & 1, wn = w >> 1;  // wn 0..1
    const int l16 = lane & 15, quad = lane >> 4;
    const int flat = blockIdx.x + (blockIdx.y << 4);  // 0..511
    const int wid = (flat & 7) * 64 + (flat >> 3);    // bijective (512%8==0)
    const int m0 = (wid >> 4) * 128, n0 = (wid & 15) * 64;
    const int srow = tid >> 3;
    const int sg = (tid & 7) ^ (srow & 7);
    const unsigned short* Ag = A + (size_t)(m0 + srow) * 1024 + sg * 8;
    unsigned short* Al = As + tid * 8;
    // B staging: 16 rows/round, f32 granules
    const int brow = tid >> 4;
    const int su = (tid & 15) ^ brow;
    const float* Bg = Wp + (size_t)(n0 + brow) * 1024 + su * 4;
    float* Blf = Bsf + tid * 4;
    const int xo8 = l16 & 7;

    f32x4 acc[4][2] = {};
    for (int k0 = 0; k0 < 1024; k0 += 64) {
        __syncthreads();
#pragma unroll
        for (int c = 0; c < 4; c++)
            glds16(Ag + (size_t)c * 32 * 1024 + k0, Al + c * 2048);
#pragma unroll
        for (int c = 0; c < 4; c++)
            glds16f(Bg + (size_t)c * 16 * 1024 + k0, Blf + c * 1024);
        __syncthreads();
#pragma unroll
        for (int kc = 0; kc < 2; kc++) {
            s16x8 bf[2];
#pragma unroll
            for (int nt = 0; nt < 2; nt++) {
                const int row = wn * 32 + nt * 16 + l16;
                const int u = kc * 8 + quad * 2;
                const int e = row & 15;
                f32x4 lo = *(const f32x4*)&Bsf[row * 64 + ((u ^ e) * 4)];
                f32x4 hi = *(const f32x4*)&Bsf[row * 64 + (((u + 1) ^ e) * 4)];
                ((unsigned int*)&bf[nt])[0] = pk_bf16(lo[0], lo[1]);
                ((unsigned int*)&bf[nt])[1] = pk_bf16(lo[2], lo[3]);
                ((unsigned int*)&bf[nt])[2] = pk_bf16(hi[0], hi[1]);
                ((unsigned int*)&bf[nt])[3] = pk_bf16(hi[2], hi[3]);
            }
#pragma unroll
            for (int mt = 0; mt < 4; mt++) {
                s16x8 af = *(const s16x8*)&As[(wm * 64 + mt * 16 + l16) * 64 +
                                              (((kc * 4 + quad) ^ xo8) * 8)];
#pragma unroll
                for (int nt = 0; nt < 2; nt++)
                    acc[mt][nt] = MFMA16(af, bf[nt], acc[mt][nt]);
            }
        }
    }
    const int lq = quad;
#pragma unroll
    for (int mt = 0; mt < 4; mt++)
#pragma unroll
        for (int nt = 0; nt < 2; nt++)
#pragma unroll
            for (int r = 0; r < 4; r++) {
                int mg = m0 + wm * 64 + mt * 16 + lq * 4 + r;
                int ng = n0 + wn * 32 + nt * 16 + l16;
                C[(size_t)mg * 1024 + ng] = acc[mt][nt][r] + bias[ng];
            }
}

// ---------------------------------------------------------------------------
// Flash attention v6 (best measured): pipelined staging.
//  K double-buffered + 1-iter-ahead prefetch; V single-buffered with counted
//  vmcnt(2) mid-barrier (K prefetch stays in flight); s_setprio around MFMA.
// Q,K row-major [B,S,D] bf16 (Q pre-scaled); V: [B,H,HD,S].
// grid: x = bh (all q-blocks of a head land on one XCD), y = q-block.
// ---------------------------------------------------------------------------
__global__ __launch_bounds__(256) void flash_attn(const unsigned short* __restrict__ Qr,
                                                  const unsigned short* __restrict__ Kr,
                                                  const unsigned short* __restrict__ Vt,
                                                  unsigned short* __restrict__ Cc) {
    __shared__ unsigned short Ks[2][64 * 64];    // [buf][key][d], double-buffered
    __shared__ unsigned short Vs[64 * 64];       // [e][s-rel], single-buffered
    constexpr int LDT = 72;
    __shared__ unsigned short P4[4][16 * LDT];   // per-wave P^T: [q][key]

    const int tid = threadIdx.x;
    const int lane = tid & 63, w = tid >> 6;
    const int l16 = lane & 15, quad = lane >> 4;
    const int bh = blockIdx.x, q0 = blockIdx.y * 64;
    const int b = bh >> 4, h = bh & 15;
    const int s_q = q0 + w * 16 + l16;           // this lane's q-row

    const unsigned short* Qp = Qr + ((size_t)(b * S_ + s_q)) * D_ + h * HD_;

    const int srow = tid >> 3;
    const int sg = (tid & 7) ^ (srow & 7);
    const unsigned short* kg = Kr + ((size_t)(b * S_ + srow)) * D_ + h * HD_ + sg * 8;
    const unsigned short* vg = Vt + (((size_t)(b * H_ + h)) * HD_ + srow) * S_ + sg * 8;
    unsigned short* Vl = Vs + tid * 8;
    unsigned short* Pw = P4[w];
    const int pbase = l16 * LDT + quad * 4;      // P store base (per-lane)
    const int xo = l16 & 7;

    // prologue: stage K tile 0 into Ks[0]
    glds16(kg, &Ks[0][tid * 8]);
    glds16(kg + (size_t)32 * D_, &Ks[0][tid * 8 + 2048]);
    kg += (size_t)64 * D_;

    s16x8 aq0 = *(const s16x8*)&Qp[quad * 8];
    s16x8 aq1 = *(const s16x8*)&Qp[32 + quad * 8];

    float l_part = 0.f;
    f32x4 o[4] = {};
    const f32x4 z4 = {0.f, 0.f, 0.f, 0.f};

    asm volatile("s_waitcnt vmcnt(0) lgkmcnt(0)\n\ts_barrier" ::: "memory");

    int cur = 0;
    for (int t = 0; t < 32; ++t) {
        const int last = (t == 31);
        // stage V(t): Vs free (all waves finished PV(t-1) before last barrier)
        glds16(vg, Vl);
        glds16(vg + (size_t)32 * S_, Vl + 2048);
        vg += 64;
        if (!last) {
            // stage K(t+1) into the other K buffer (read slot freed at iter t-1)
            unsigned short* Kn = &Ks[cur ^ 1][tid * 8];
            glds16(kg, Kn);
            glds16(kg + (size_t)32 * D_, Kn + 2048);
            kg += (size_t)64 * D_;
        }

        // scores^T on Ks[cur]: D[key][q] = K·Q^T ; keys g*16+quad*4+r, col q=l16
        const unsigned short* Kc_ = &Ks[cur][0];
        __builtin_amdgcn_s_setprio(1);
#pragma unroll
        for (int g = 0; g < 4; g++) {
            int row = g * 16 + l16;
            s16x8 kb0 = *(const s16x8*)&Kc_[row * 64 + ((quad ^ xo) * 8)];
            s16x8 kb1 = *(const s16x8*)&Kc_[row * 64 + (((4 + quad) ^ xo) * 8)];
            f32x4 sc = MFMA16(kb0, aq0, z4);
            sc = MFMA16(kb1, aq1, sc);
            float e0 = exp2f(sc[0]), e1 = exp2f(sc[1]);
            float e2 = exp2f(sc[2]), e3 = exp2f(sc[3]);
            l_part += (e0 + e1) + (e2 + e3);
            u32x2 pv;
            pv[0] = pk_bf16(e0, e1);
            pv[1] = pk_bf16(e2, e3);
            *(u32x2*)&Pw[pbase + g * 16] = pv;   // 4 contig keys, 8B store
        }
        __builtin_amdgcn_s_setprio(0);
        // P as B-operand for PV: B[k=key][n=q] = Pw[q=l16][key] (same-wave, DS in-order)
        s16x8 pB0 = *(const s16x8*)&Pw[l16 * LDT + quad * 8];
        s16x8 pB1 = *(const s16x8*)&Pw[l16 * LDT + 32 + quad * 8];

        // mid-iter: V(t) landed (leave the 2 newer K(t+1) glds in flight), all waves sync
        if (!last)
            asm volatile("s_waitcnt vmcnt(2)\n\ts_barrier" ::: "memory");
        else
            asm volatile("s_waitcnt vmcnt(0)\n\ts_barrier" ::: "memory");

        // o^T[e][q] += V^T · P^T
        __builtin_amdgcn_s_setprio(1);
#pragma unroll
        for (int tt = 0; tt < 4; tt++) {
            int row = tt * 16 + l16;
            s16x8 v0 = *(const s16x8*)&Vs[row * 64 + ((quad ^ xo) * 8)];
            s16x8 v1 = *(const s16x8*)&Vs[row * 64 + (((4 + quad) ^ xo) * 8)];
            o[tt] = MFMA16(v0, pB0, o[tt]);
            o[tt] = MFMA16(v1, pB1, o[tt]);
        }
        __builtin_amdgcn_s_setprio(0);
        // end-of-iter: my LDS reads retired (Ks[cur]/Vs safe to overwrite next iter),
        // K(t+1) landed (had a full iteration of slack)
        asm volatile("s_waitcnt vmcnt(0) lgkmcnt(0)\n\ts_barrier" ::: "memory");
        cur ^= 1;
    }

    float l = l_part;
    l += __shfl_xor(l, 16);
    l += __shfl_xor(l, 32);
    float rinv = 1.0f / l;
    unsigned short* Cp = Cc + ((size_t)(b * S_ + s_q)) * D_ + h * HD_;
#pragma unroll
    for (int t = 0; t < 4; t++) {
        u32x2 ov;
        ov[0] = pk_bf16(o[t][0] * rinv, o[t][1] * rinv);
        ov[1] = pk_bf16(o[t][2] * rinv, o[t][3] * rinv);
        *(u32x2*)&Cp[t * 16 + quad * 4] = ov;
    }
}

// ---------------------------------------------------------------------------
extern "C" void kernel_launch(void* const* d_in, const int* in_sizes, int n_in,
                              void* d_out, int out_size, void* d_ws, size_t ws_size,
                              hipStream_t stream) {
    const float* K_in = (const float*)d_in[0];
    const float* V_in = (const float*)d_in[1];
    const float* Q_in = (const float*)d_in[2];
    const float* Wk   = (const float*)d_in[3];
    const float* bk   = (const float*)d_in[4];
    const float* Wq   = (const float*)d_in[5];
    const float* bq   = (const float*)d_in[6];
    const float* Wv   = (const float*)d_in[7];
    const float* bv   = (const float*)d_in[8];
    const float* Wp   = (const float*)d_in[9];
    const float* bp   = (const float*)d_in[10];

    unsigned short* ws16 = (unsigned short*)d_ws;
    const size_t MC = 1u << 20;
    unsigned short* Wt3 = ws16;            // 3M bf16 transposed QKV weights
    unsigned short* Qr  = Wt3 + 3 * MC;    // 4M [B,S,D] projected, pre-scaled
    unsigned short* Kr  = Qr + 4 * MC;     // 4M [B,S,D]
    unsigned short* Vt  = Kr + 4 * MC;     // 4M [B,H,HD,S]
    unsigned short* Cc  = Vt + 4 * MC;     // 4M [B,S,D] attention output

    transpose_w3<<<dim3(64, 1, 3), 256, 0, stream>>>(Wq, Wk, Wv, Wt3);

    gemm_qkv<<<dim3(8, 32, 3), 256, 0, stream>>>(Q_in, K_in, V_in, Wt3, bq, bk, bv,
                                                 Qr, Kr, Vt);

    flash_attn<<<dim3(32, 32), 256, 0, stream>>>(Qr, Kr, Vt, Cc);

    gemm_out<<<dim3(16, 32), 256, 0, stream>>>(Cc, Wp, bp, (float*)d_out);
}